// Round 23
// baseline (113.737 us; speedup 1.0000x reference)
//
#include <hip/hip_runtime.h>
#include <hip/hip_bf16.h>

typedef short short8 __attribute__((ext_vector_type(8)));
typedef short short4v __attribute__((ext_vector_type(4)));
typedef float floatx4 __attribute__((ext_vector_type(4)));

#define EMB 768
#define DH 96
#define NHEAD 8
#define NBATCH 32
#define SEQ 512
#define MROWS (NBATCH * SEQ)   // 16384

__device__ __forceinline__ unsigned short f2bf(float x) {
    __hip_bfloat16 h = __float2bfloat16(x);
    union { __hip_bfloat16 b; unsigned short u; } c;
    c.b = h;
    return c.u;
}

// ---------- transpose+convert weights: wt[h*96+d][e] = w[h][e][d] ----------
__global__ __launch_bounds__(256) void cvt_w_kernel(
    const float* __restrict__ wk, const float* __restrict__ wq,
    unsigned short* __restrict__ wtk, unsigned short* __restrict__ wtq)
{
    __shared__ float ws[64][97];
    const int h = blockIdx.x, et = blockIdx.y;
    const float* wsrc = (blockIdx.z ? wq : wk) + (size_t)h * EMB * DH;
    unsigned short* o = blockIdx.z ? wtq : wtk;
    const int t = threadIdx.x;
    const int e0 = et * 64;
    #pragma unroll
    for (int i = 0; i < 6; ++i) {
        int f = i * 256 + t;              // 1536 tasks: 64 e-rows x 24 float4
        int e = f / 24, c = f % 24;
        float4 v = *(const float4*)(wsrc + (size_t)(e0 + e) * DH + c * 4);
        ws[e][c*4+0] = v.x; ws[e][c*4+1] = v.y; ws[e][c*4+2] = v.z; ws[e][c*4+3] = v.w;
    }
    __syncthreads();
    #pragma unroll
    for (int i = 0; i < 3; ++i) {
        int f = i * 256 + t;              // 768 tasks: 96 d x 8 chunks
        int d = f >> 3, c8 = f & 7;
        short8 v;
        #pragma unroll
        for (int j = 0; j < 8; ++j) v[j] = (short)f2bf(ws[c8*8+j][d]);
        *(short8*)(o + (size_t)(h*DH + d) * EMB + e0 + c8*8) = v;
    }
}

// ---------- projection GEMM (R22-proven): B staging via global_load_lds ----------
__global__ __launch_bounds__(256, 2) void proj_kernel(
    const float* __restrict__ x,
    const unsigned short* __restrict__ wt,
    unsigned short* __restrict__ xp)
{
    __shared__ char As[16384];   // [128 rows][8 slots of 16B], slot ^= row&7
    __shared__ char Bs[32768];   // [256 rows][8 slots of 16B], slot ^= row&7 (via src)
    const int t = threadIdx.x;
    const int wv = t >> 6, l = t & 63;
    const int lr = l & 15, lg = l >> 4, l7 = l & 7;
    const int mt = blockIdx.x * 128, nt = blockIdx.y * 256;
    const int mw = (wv >> 1) * 64, nw = (wv & 1) * 128;

    floatx4 acc[4][8];
    #pragma unroll
    for (int a = 0; a < 4; ++a)
        #pragma unroll
        for (int b = 0; b < 8; ++b) acc[a][b] = (floatx4){0.f, 0.f, 0.f, 0.f};

    for (int kt = 0; kt < EMB / 64; ++kt) {
        __syncthreads();
        #pragma unroll
        for (int i = 0; i < 8; ++i) {
            int f = i * 256 + t;
            int row = f >> 3, sp = f & 7;
            int s = sp ^ (row & 7);
            const unsigned short* srcB = wt + (size_t)(nt + row) * EMB + kt*64 + s*8;
            __builtin_amdgcn_global_load_lds(
                (const __attribute__((address_space(1))) void*)srcB,
                (__attribute__((address_space(3))) void*)(Bs + f * 16), 16, 0, 0);
        }
        #pragma unroll
        for (int i = 0; i < 4; ++i) {
            int f = i * 256 + t;
            int row = f >> 3, s = f & 7;
            const float* xs = x + (size_t)(mt + row) * EMB + kt*64 + s*8;
            float4 ga = *(const float4*)xs;
            float4 gb = *(const float4*)(xs + 4);
            union { unsigned short h[8]; short8 s8; } pk;
            pk.h[0] = f2bf(ga.x); pk.h[1] = f2bf(ga.y);
            pk.h[2] = f2bf(ga.z); pk.h[3] = f2bf(ga.w);
            pk.h[4] = f2bf(gb.x); pk.h[5] = f2bf(gb.y);
            pk.h[6] = f2bf(gb.z); pk.h[7] = f2bf(gb.w);
            *(short8*)(As + row*128 + ((s ^ (row & 7)) * 16)) = pk.s8;
        }
        __syncthreads();   // drains vmcnt (DMA) + lgkmcnt (ds_writes)
        #pragma unroll
        for (int ks = 0; ks < 2; ++ks) {
            const int sl = (ks*4 + lg) ^ l7;
            short8 af[4], bf[8];
            #pragma unroll
            for (int mf = 0; mf < 4; ++mf)
                af[mf] = *(const short8*)(As + (mw + 16*mf + lr) * 128 + sl*16);
            #pragma unroll
            for (int nf = 0; nf < 8; ++nf)
                bf[nf] = *(const short8*)(Bs + (nw + 16*nf + lr) * 128 + sl*16);
            #pragma unroll
            for (int mf = 0; mf < 4; ++mf)
                #pragma unroll
                for (int nf = 0; nf < 8; ++nf)
                    acc[mf][nf] = __builtin_amdgcn_mfma_f32_16x16x32_bf16(
                        af[mf], bf[nf], acc[mf][nf], 0, 0, 0);
        }
    }
    #pragma unroll
    for (int mf = 0; mf < 4; ++mf)
        #pragma unroll
        for (int r = 0; r < 4; ++r) {
            int m = mt + mw + 16*mf + lg*4 + r;
            unsigned short* op = xp + (size_t)m * EMB + nt + nw + lr;
            #pragma unroll
            for (int nf = 0; nf < 8; ++nf) op[16*nf] = f2bf(acc[mf][nf][r]);
        }
}

// ---------- fused attention: R22 schedule + Ks staged via global_load_lds ----------
// Ks task f (row=f/12, pos sp=f%12) is LINEAR in LDS (dest f*16); the mod-12
// swizzle moves to the global source: s = (sp - row) mod 12. Read side unchanged.
// Kt2 transpose keeps the reg path (pg loads re-read same lines -> L2 hit).
__global__ __launch_bounds__(512) void attn_kernel(
    const unsigned short* __restrict__ kx,   // [16384][768] bf16
    const unsigned short* __restrict__ qx,   // [16384][768] bf16
    float* __restrict__ out)
{
    __shared__ char KsB[2 * 12288];  // [buf][64 kr][12 pos], pos holds d-slot (sp-row)%12
    __shared__ char KtB[2 * 12288];  // [buf][16 c][96 granules 8B], g = d ^ 5*(c&3)
    const int t = threadIdx.x;
    const int wv = t >> 6, l = t & 63;      // wv 0..7
    const int lr = l & 15, lg = l >> 4;
    const int q0 = blockIdx.x * 256, b = blockIdx.y, h = blockIdx.z;
    const size_t bq = (size_t)b * SEQ;
    const int hcol = h * DH;
    // p = exp(s/sqrt(96) - 12) = exp2(s*scale2 + shift2)
    const float scale2 = 0.14724446865f;     // log2(e)/sqrt(96)
    const float shift2 = -17.312340490668f;  // -12*log2(e)

    // Kt2 staging task (valid when t < 384): 32 row-pairs x 12 d-slots
    const bool stv = (t < 384);
    const int rp = t / 12, ss = t - rp * 12;
    const int r0 = rp * 2;
    // Ks DMA tasks: f1 = t (all), f2 = 512+t (t<256)
    const int k1row = t / 12, k1sp = t - k1row * 12;
    const int k1s = (k1sp + 132 - k1row) % 12;
    const int f2 = 512 + t;
    const int k2row = f2 / 12, k2sp = f2 - k2row * 12;
    const int k2s = (k2sp + 132 - k2row) % 12;

    short8 qf[2][3];
    #pragma unroll
    for (int mf = 0; mf < 2; ++mf)
        #pragma unroll
        for (int ks = 0; ks < 3; ++ks)
            qf[mf][ks] = *(const short8*)(qx
                + (bq + q0 + 32*wv + 16*mf + lr) * EMB + hcol + ks*32 + lg*8);

    floatx4 of[2][6];
    #pragma unroll
    for (int mf = 0; mf < 2; ++mf)
        #pragma unroll
        for (int dt = 0; dt < 6; ++dt) of[mf][dt] = (floatx4){0.f, 0.f, 0.f, 0.f};
    float lsum[2] = {0.f, 0.f};

    // prologue: DMA Ks tile 0 -> buf0; load pg (tile 0) for Kt2
    {
        const unsigned short* s1 = kx + (bq + k1row) * EMB + hcol + k1s*8;
        __builtin_amdgcn_global_load_lds(
            (const __attribute__((address_space(1))) void*)s1,
            (__attribute__((address_space(3))) void*)(KsB + t * 16), 16, 0, 0);
        if (t < 256) {
            const unsigned short* s2 = kx + (bq + k2row) * EMB + hcol + k2s*8;
            __builtin_amdgcn_global_load_lds(
                (const __attribute__((address_space(1))) void*)s2,
                (__attribute__((address_space(3))) void*)(KsB + f2 * 16), 16, 0, 0);
        }
    }
    short8 pg0, pg1;
    if (stv) {
        const unsigned short* src = kx + (bq + r0) * EMB + hcol + ss*8;
        pg0 = *(const short8*)src;
        pg1 = *(const short8*)(src + EMB);
    }

    int cur = 0;
    for (int kt = 0; kt < SEQ / 64; ++kt) {
        // write Kt2 (transpose) from staged regs into buffer cur
        if (stv) {
            char* Tc = KtB + cur * 12288;
            const int c = rp >> 1, tau = 5 * (c & 3);
            char* kb = Tc + c*768 + ((rp & 1) << 2);
            #pragma unroll
            for (int j = 0; j < 8; ++j) {
                int d = ss*8 + j;
                unsigned int pr = (unsigned int)(unsigned short)pg0[j]
                                | ((unsigned int)(unsigned short)pg1[j] << 16);
                *(unsigned int*)(kb + ((d ^ tau) << 3)) = pr;
            }
        }
        __syncthreads();   // drains Ks DMA (vmcnt) + Kt2 writes; prior compute done

        // issue next tile's Ks DMA (-> buf cur^1) + pg loads; fly under MFMAs
        if (kt < SEQ/64 - 1) {
            char* Kn = KsB + (cur ^ 1) * 12288;
            const size_t rowbase = bq + (kt+1)*64;
            const unsigned short* s1 = kx + (rowbase + k1row) * EMB + hcol + k1s*8;
            __builtin_amdgcn_global_load_lds(
                (const __attribute__((address_space(1))) void*)s1,
                (__attribute__((address_space(3))) void*)(Kn + t * 16), 16, 0, 0);
            if (t < 256) {
                const unsigned short* s2 = kx + (rowbase + k2row) * EMB + hcol + k2s*8;
                __builtin_amdgcn_global_load_lds(
                    (const __attribute__((address_space(1))) void*)s2,
                    (__attribute__((address_space(3))) void*)(Kn + f2 * 16), 16, 0, 0);
            }
            if (stv) {
                const unsigned short* src = kx + (rowbase + r0) * EMB + hcol + ss*8;
                pg0 = *(const short8*)src;
                pg1 = *(const short8*)(src + EMB);
            }
        }

        const char* Kc = KsB + cur * 12288;
        const char* Tc = KtB + cur * 12288;

        // S^T = mfma(A=K, B=Q): sf[mf][nf][r] = S[q=32wv+16mf+lr][kr=16nf+4lg+r]
        floatx4 sf[2][4];
        #pragma unroll
        for (int mf = 0; mf < 2; ++mf)
            #pragma unroll
            for (int nf = 0; nf < 4; ++nf) sf[mf][nf] = (floatx4){0.f, 0.f, 0.f, 0.f};
        #pragma unroll
        for (int ks = 0; ks < 3; ++ks) {
            short8 bk[4];
            #pragma unroll
            for (int nf = 0; nf < 4; ++nf) {
                int row = 16*nf + lr;
                bk[nf] = *(const short8*)(Kc + row*192 + ((ks*4 + lg + row) % 12) * 16);
            }
            #pragma unroll
            for (int mf = 0; mf < 2; ++mf)
                #pragma unroll
                for (int nf = 0; nf < 4; ++nf)
                    sf[mf][nf] = __builtin_amdgcn_mfma_f32_16x16x32_bf16(
                        bk[nf], qf[mf][ks], sf[mf][nf], 0, 0, 0);
        }

        // softmax (fixed-shift, exact): p = exp2(s*scale2 + shift2), in place
        #pragma unroll
        for (int mf = 0; mf < 2; ++mf)
            #pragma unroll
            for (int nf = 0; nf < 4; ++nf)
                #pragma unroll
                for (int r = 0; r < 4; ++r) {
                    float p = __builtin_amdgcn_exp2f(fmaf(sf[mf][nf][r], scale2, shift2));
                    sf[mf][nf][r] = p;
                    lsum[mf] += p;
                }

        // O += P.V : A = own-reg P (sigma map), B = Kt b64 pairs
        #pragma unroll
        for (int ks2 = 0; ks2 < 2; ++ks2) {
            union { unsigned short hsh[8]; short8 s8; } ap[2];
            #pragma unroll
            for (int mf = 0; mf < 2; ++mf)
                #pragma unroll
                for (int j = 0; j < 8; ++j)
                    ap[mf].hsh[j] = f2bf(sf[mf][2*ks2 + (j >> 2)][j & 3]);
            const int cbase = (8*ks2 + lg) * 768;
            const int tau = 5 * lg;
            #pragma unroll
            for (int dt = 0; dt < 6; ++dt) {
                const int gofs = ((16*dt + lr) ^ tau) << 3;
                short4v lo = *(const short4v*)(Tc + cbase + gofs);
                short4v hi = *(const short4v*)(Tc + cbase + 3072 + gofs);
                short8 bv;
                bv[0] = lo[0]; bv[1] = lo[1]; bv[2] = lo[2]; bv[3] = lo[3];
                bv[4] = hi[0]; bv[5] = hi[1]; bv[6] = hi[2]; bv[7] = hi[3];
                #pragma unroll
                for (int mf = 0; mf < 2; ++mf)
                    of[mf][dt] = __builtin_amdgcn_mfma_f32_16x16x32_bf16(
                        ap[mf].s8, bv, of[mf][dt], 0, 0, 0);
            }
        }
        cur ^= 1;
    }

    float invq[2];
    #pragma unroll
    for (int mf = 0; mf < 2; ++mf) {
        float v = lsum[mf];
        v += __shfl_xor(v, 16);
        v += __shfl_xor(v, 32);
        invq[mf] = 1.0f / v;
    }
    #pragma unroll
    for (int mf = 0; mf < 2; ++mf)
        #pragma unroll
        for (int r = 0; r < 4; ++r) {
            float inv = __shfl(invq[mf], 4*lg + r);
            int q = q0 + 32*wv + 16*mf + 4*lg + r;
            float* op = out + (bq + q) * (NHEAD*DH) + hcol + lr;
            #pragma unroll
            for (int dt = 0; dt < 6; ++dt) op[16*dt] = of[mf][dt][r] * inv;
        }
}

extern "C" void kernel_launch(void* const* d_in, const int* in_sizes, int n_in,
                              void* d_out, int out_size, void* d_ws, size_t ws_size,
                              hipStream_t stream) {
    const float* kin = (const float*)d_in[0];
    const float* qin = (const float*)d_in[1];
    const float* wk  = (const float*)d_in[2];
    const float* wq  = (const float*)d_in[3];
    float* out = (float*)d_out;

    unsigned short* wsu = (unsigned short*)d_ws;
    const size_t SZX = (size_t)MROWS * EMB;          // 12,582,912 elems
    unsigned short* kxb = wsu;                        // projected K (bf16) [16384][768]
    unsigned short* qxb = wsu + SZX;                  // projected Q (bf16)
    unsigned short* wtk = wsu + 2*SZX;                // W_k^T [768][768]
    unsigned short* wtq = wtk + (size_t)EMB * (NHEAD*DH);

    cvt_w_kernel<<<dim3(NHEAD, EMB/64, 2), 256, 0, stream>>>(wk, wq, wtk, wtq);
    proj_kernel<<<dim3(MROWS/128, (NHEAD*DH)/256), 256, 0, stream>>>(kin, wtk, kxb);
    proj_kernel<<<dim3(MROWS/128, (NHEAD*DH)/256), 256, 0, stream>>>(qin, wtq, qxb);
    attn_kernel<<<dim3(SEQ/256, NBATCH, NHEAD), 512, 0, stream>>>(kxb, qxb, out);
}

// Round 24
// 109.805 us; speedup vs baseline: 1.0358x; 1.0358x over previous
//
#include <hip/hip_runtime.h>
#include <hip/hip_bf16.h>

typedef short short8 __attribute__((ext_vector_type(8)));
typedef short short4v __attribute__((ext_vector_type(4)));
typedef float floatx4 __attribute__((ext_vector_type(4)));

#define EMB 768
#define DH 96
#define NHEAD 8
#define NBATCH 32
#define SEQ 512
#define MROWS (NBATCH * SEQ)   // 16384

__device__ __forceinline__ unsigned short f2bf(float x) {
    __hip_bfloat16 h = __float2bfloat16(x);
    union { __hip_bfloat16 b; unsigned short u; } c;
    c.b = h;
    return c.u;
}

// ---------- transpose+convert weights: wt[h*96+d][e] = w[h][e][d] ----------
__global__ __launch_bounds__(256) void cvt_w_kernel(
    const float* __restrict__ wk, const float* __restrict__ wq,
    unsigned short* __restrict__ wtk, unsigned short* __restrict__ wtq)
{
    __shared__ float ws[64][97];
    const int h = blockIdx.x, et = blockIdx.y;
    const float* wsrc = (blockIdx.z ? wq : wk) + (size_t)h * EMB * DH;
    unsigned short* o = blockIdx.z ? wtq : wtk;
    const int t = threadIdx.x;
    const int e0 = et * 64;
    #pragma unroll
    for (int i = 0; i < 6; ++i) {
        int f = i * 256 + t;              // 1536 tasks: 64 e-rows x 24 float4
        int e = f / 24, c = f % 24;
        float4 v = *(const float4*)(wsrc + (size_t)(e0 + e) * DH + c * 4);
        ws[e][c*4+0] = v.x; ws[e][c*4+1] = v.y; ws[e][c*4+2] = v.z; ws[e][c*4+3] = v.w;
    }
    __syncthreads();
    #pragma unroll
    for (int i = 0; i < 3; ++i) {
        int f = i * 256 + t;              // 768 tasks: 96 d x 8 chunks
        int d = f >> 3, c8 = f & 7;
        short8 v;
        #pragma unroll
        for (int j = 0; j < 8; ++j) v[j] = (short)f2bf(ws[c8*8+j][d]);
        *(short8*)(o + (size_t)(h*DH + d) * EMB + e0 + c8*8) = v;
    }
}

// ---------- projection GEMM (R22-proven): B staging via global_load_lds ----------
// B tile DMAs directly global->LDS (linear dest, pre-swizzled global source);
// removes the VGPR round-trip + 8 ds_writes per thread per k-tile. A staging
// keeps the reg path (needs f32->bf16 cvt in flight).
__global__ __launch_bounds__(256, 2) void proj_kernel(
    const float* __restrict__ x,
    const unsigned short* __restrict__ wt,
    unsigned short* __restrict__ xp)
{
    __shared__ char As[16384];   // [128 rows][8 slots of 16B], slot ^= row&7
    __shared__ char Bs[32768];   // [256 rows][8 slots of 16B], slot ^= row&7 (via src)
    const int t = threadIdx.x;
    const int wv = t >> 6, l = t & 63;
    const int lr = l & 15, lg = l >> 4, l7 = l & 7;
    const int mt = blockIdx.x * 128, nt = blockIdx.y * 256;
    const int mw = (wv >> 1) * 64, nw = (wv & 1) * 128;

    floatx4 acc[4][8];
    #pragma unroll
    for (int a = 0; a < 4; ++a)
        #pragma unroll
        for (int b = 0; b < 8; ++b) acc[a][b] = (floatx4){0.f, 0.f, 0.f, 0.f};

    for (int kt = 0; kt < EMB / 64; ++kt) {
        __syncthreads();
        // B: 2048 tasks DMA'd; LDS dest linear f*16 (wave-contiguous 1KB),
        // global slot pre-swizzled s = sp ^ (row&7)  -> same final layout.
        #pragma unroll
        for (int i = 0; i < 8; ++i) {
            int f = i * 256 + t;
            int row = f >> 3, sp = f & 7;
            int s = sp ^ (row & 7);
            const unsigned short* srcB = wt + (size_t)(nt + row) * EMB + kt*64 + s*8;
            __builtin_amdgcn_global_load_lds(
                (const __attribute__((address_space(1))) void*)srcB,
                (__attribute__((address_space(3))) void*)(Bs + f * 16), 16, 0, 0);
        }
        // A: 1024 tasks (128 rows x 8 slots), f32 load + cvt (reg path)
        #pragma unroll
        for (int i = 0; i < 4; ++i) {
            int f = i * 256 + t;
            int row = f >> 3, s = f & 7;
            const float* xs = x + (size_t)(mt + row) * EMB + kt*64 + s*8;
            float4 ga = *(const float4*)xs;
            float4 gb = *(const float4*)(xs + 4);
            union { unsigned short h[8]; short8 s8; } pk;
            pk.h[0] = f2bf(ga.x); pk.h[1] = f2bf(ga.y);
            pk.h[2] = f2bf(ga.z); pk.h[3] = f2bf(ga.w);
            pk.h[4] = f2bf(gb.x); pk.h[5] = f2bf(gb.y);
            pk.h[6] = f2bf(gb.z); pk.h[7] = f2bf(gb.w);
            *(short8*)(As + row*128 + ((s ^ (row & 7)) * 16)) = pk.s8;
        }
        __syncthreads();   // drains vmcnt (DMA) + lgkmcnt (ds_writes)
        #pragma unroll
        for (int ks = 0; ks < 2; ++ks) {
            const int sl = (ks*4 + lg) ^ l7;
            short8 af[4], bf[8];
            #pragma unroll
            for (int mf = 0; mf < 4; ++mf)
                af[mf] = *(const short8*)(As + (mw + 16*mf + lr) * 128 + sl*16);
            #pragma unroll
            for (int nf = 0; nf < 8; ++nf)
                bf[nf] = *(const short8*)(Bs + (nw + 16*nf + lr) * 128 + sl*16);
            #pragma unroll
            for (int mf = 0; mf < 4; ++mf)
                #pragma unroll
                for (int nf = 0; nf < 8; ++nf)
                    acc[mf][nf] = __builtin_amdgcn_mfma_f32_16x16x32_bf16(
                        af[mf], bf[nf], acc[mf][nf], 0, 0, 0);
        }
    }
    #pragma unroll
    for (int mf = 0; mf < 4; ++mf)
        #pragma unroll
        for (int r = 0; r < 4; ++r) {
            int m = mt + mw + 16*mf + lg*4 + r;
            unsigned short* op = xp + (size_t)m * EMB + nt + nw + lr;
            #pragma unroll
            for (int nf = 0; nf < 8; ++nf) op[16*nf] = f2bf(acc[mf][nf][r]);
        }
}

// ---------- fused attention (R18/R19/R22-proven): dbuf + issue-early + exp2 ----------
__global__ __launch_bounds__(512) void attn_kernel(
    const unsigned short* __restrict__ kx,   // [16384][768] bf16
    const unsigned short* __restrict__ qx,   // [16384][768] bf16
    float* __restrict__ out)
{
    __shared__ char KsB[2 * 12288];  // [buf][64 kr][12 slots], slot' = (s+row)%12
    __shared__ char KtB[2 * 12288];  // [buf][16 c][96 granules 8B], g = d ^ 5*(c&3)
    const int t = threadIdx.x;
    const int wv = t >> 6, l = t & 63;      // wv 0..7
    const int lr = l & 15, lg = l >> 4;
    const int q0 = blockIdx.x * 256, b = blockIdx.y, h = blockIdx.z;
    const size_t bq = (size_t)b * SEQ;
    const int hcol = h * DH;
    // p = exp(s/sqrt(96) - 12) = exp2(s*scale2 + shift2)
    const float scale2 = 0.14724446865f;     // log2(e)/sqrt(96)
    const float shift2 = -17.312340490668f;  // -12*log2(e)

    // staging task descriptor (valid when t < 384): 32 row-pairs x 12 d-slots
    const bool stv = (t < 384);
    const int rp = t / 12, ss = t - rp * 12;
    const int r0 = rp * 2;

    short8 qf[2][3];
    #pragma unroll
    for (int mf = 0; mf < 2; ++mf)
        #pragma unroll
        for (int ks = 0; ks < 3; ++ks)
            qf[mf][ks] = *(const short8*)(qx
                + (bq + q0 + 32*wv + 16*mf + lr) * EMB + hcol + ks*32 + lg*8);

    floatx4 of[2][6];
    #pragma unroll
    for (int mf = 0; mf < 2; ++mf)
        #pragma unroll
        for (int dt = 0; dt < 6; ++dt) of[mf][dt] = (floatx4){0.f, 0.f, 0.f, 0.f};
    float lsum[2] = {0.f, 0.f};

    // prologue: load tile 0 to regs
    short8 pg0, pg1;
    if (stv) {
        const unsigned short* src = kx + (bq + r0) * EMB + hcol + ss*8;
        pg0 = *(const short8*)src;
        pg1 = *(const short8*)(src + EMB);
    }

    int cur = 0;
    for (int kt = 0; kt < SEQ / 64; ++kt) {
        // write staged regs into buffer cur
        if (stv) {
            char* Kc = KsB + cur * 12288;
            char* Tc = KtB + cur * 12288;
            *(short8*)(Kc + r0*192 + ((ss + r0) % 12) * 16) = pg0;
            *(short8*)(Kc + (r0+1)*192 + ((ss + r0 + 1) % 12) * 16) = pg1;
            const int c = rp >> 1, tau = 5 * (c & 3);
            char* kb = Tc + c*768 + ((rp & 1) << 2);
            #pragma unroll
            for (int j = 0; j < 8; ++j) {
                int d = ss*8 + j;
                unsigned int pr = (unsigned int)(unsigned short)pg0[j]
                                | ((unsigned int)(unsigned short)pg1[j] << 16);
                *(unsigned int*)(kb + ((d ^ tau) << 3)) = pr;
            }
        }
        __syncthreads();   // tile kt visible; prior compute (kt-1, cur^1) done

        // issue next tile's loads; they complete under the MFMAs below
        if (kt < SEQ/64 - 1 && stv) {
            const unsigned short* src = kx + (bq + (kt+1)*64 + r0) * EMB + hcol + ss*8;
            pg0 = *(const short8*)src;
            pg1 = *(const short8*)(src + EMB);
        }

        const char* Kc = KsB + cur * 12288;
        const char* Tc = KtB + cur * 12288;

        // S^T = mfma(A=K, B=Q): sf[mf][nf][r] = S[q=32wv+16mf+lr][kr=16nf+4lg+r]
        floatx4 sf[2][4];
        #pragma unroll
        for (int mf = 0; mf < 2; ++mf)
            #pragma unroll
            for (int nf = 0; nf < 4; ++nf) sf[mf][nf] = (floatx4){0.f, 0.f, 0.f, 0.f};
        #pragma unroll
        for (int ks = 0; ks < 3; ++ks) {
            short8 bk[4];
            #pragma unroll
            for (int nf = 0; nf < 4; ++nf) {
                int row = 16*nf + lr;
                bk[nf] = *(const short8*)(Kc + row*192 + ((ks*4 + lg + row) % 12) * 16);
            }
            #pragma unroll
            for (int mf = 0; mf < 2; ++mf)
                #pragma unroll
                for (int nf = 0; nf < 4; ++nf)
                    sf[mf][nf] = __builtin_amdgcn_mfma_f32_16x16x32_bf16(
                        bk[nf], qf[mf][ks], sf[mf][nf], 0, 0, 0);
        }

        // softmax (fixed-shift, exact): p = exp2(s*scale2 + shift2), in place
        #pragma unroll
        for (int mf = 0; mf < 2; ++mf)
            #pragma unroll
            for (int nf = 0; nf < 4; ++nf)
                #pragma unroll
                for (int r = 0; r < 4; ++r) {
                    float p = __builtin_amdgcn_exp2f(fmaf(sf[mf][nf][r], scale2, shift2));
                    sf[mf][nf][r] = p;
                    lsum[mf] += p;
                }

        // O += P.V : A = own-reg P (sigma map), B = Kt b64 pairs
        #pragma unroll
        for (int ks2 = 0; ks2 < 2; ++ks2) {
            union { unsigned short hsh[8]; short8 s8; } ap[2];
            #pragma unroll
            for (int mf = 0; mf < 2; ++mf)
                #pragma unroll
                for (int j = 0; j < 8; ++j)
                    ap[mf].hsh[j] = f2bf(sf[mf][2*ks2 + (j >> 2)][j & 3]);
            const int cbase = (8*ks2 + lg) * 768;
            const int tau = 5 * lg;
            #pragma unroll
            for (int dt = 0; dt < 6; ++dt) {
                const int gofs = ((16*dt + lr) ^ tau) << 3;
                short4v lo = *(const short4v*)(Tc + cbase + gofs);
                short4v hi = *(const short4v*)(Tc + cbase + 3072 + gofs);
                short8 bv;
                bv[0] = lo[0]; bv[1] = lo[1]; bv[2] = lo[2]; bv[3] = lo[3];
                bv[4] = hi[0]; bv[5] = hi[1]; bv[6] = hi[2]; bv[7] = hi[3];
                #pragma unroll
                for (int mf = 0; mf < 2; ++mf)
                    of[mf][dt] = __builtin_amdgcn_mfma_f32_16x16x32_bf16(
                        ap[mf].s8, bv, of[mf][dt], 0, 0, 0);
            }
        }
        cur ^= 1;
    }

    float invq[2];
    #pragma unroll
    for (int mf = 0; mf < 2; ++mf) {
        float v = lsum[mf];
        v += __shfl_xor(v, 16);
        v += __shfl_xor(v, 32);
        invq[mf] = 1.0f / v;
    }
    #pragma unroll
    for (int mf = 0; mf < 2; ++mf)
        #pragma unroll
        for (int r = 0; r < 4; ++r) {
            float inv = __shfl(invq[mf], 4*lg + r);
            int q = q0 + 32*wv + 16*mf + 4*lg + r;
            float* op = out + (bq + q) * (NHEAD*DH) + hcol + lr;
            #pragma unroll
            for (int dt = 0; dt < 6; ++dt) op[16*dt] = of[mf][dt][r] * inv;
        }
}

extern "C" void kernel_launch(void* const* d_in, const int* in_sizes, int n_in,
                              void* d_out, int out_size, void* d_ws, size_t ws_size,
                              hipStream_t stream) {
    const float* kin = (const float*)d_in[0];
    const float* qin = (const float*)d_in[1];
    const float* wk  = (const float*)d_in[2];
    const float* wq  = (const float*)d_in[3];
    float* out = (float*)d_out;

    unsigned short* wsu = (unsigned short*)d_ws;
    const size_t SZX = (size_t)MROWS * EMB;          // 12,582,912 elems
    unsigned short* kxb = wsu;                        // projected K (bf16) [16384][768]
    unsigned short* qxb = wsu + SZX;                  // projected Q (bf16)
    unsigned short* wtk = wsu + 2*SZX;                // W_k^T [768][768]
    unsigned short* wtq = wtk + (size_t)EMB * (NHEAD*DH);

    cvt_w_kernel<<<dim3(NHEAD, EMB/64, 2), 256, 0, stream>>>(wk, wq, wtk, wtq);
    proj_kernel<<<dim3(MROWS/128, (NHEAD*DH)/256), 256, 0, stream>>>(kin, wtk, kxb);
    proj_kernel<<<dim3(MROWS/128, (NHEAD*DH)/256), 256, 0, stream>>>(qin, wtq, qxb);
    attn_kernel<<<dim3(SEQ/256, NBATCH, NHEAD), 512, 0, stream>>>(kxb, qxb, out);
}